// Round 18
// baseline (165.188 us; speedup 1.0000x reference)
//
#include <hip/hip_runtime.h>
#include <hip/hip_bf16.h>

// Problem constants (from reference)
#define NN 50000
#define NE 800000
#define HD 128
#define NB 391              // buckets of 128 dst nodes: (NN+127)>>7
#define CAP 4096            // fixed bucket capacity: mean 2048, sigma ~45 -> +45 sigma
#define PQ_BLOCKS 391      // (NN+127)/128
#define SCAT_BLOCKS ((NE + 8191) / 8192)

typedef unsigned short u16;
typedef unsigned char u8;
typedef unsigned int u32;
typedef __attribute__((ext_vector_type(8))) short short8;
typedef __attribute__((ext_vector_type(4))) float floatx4;
typedef __attribute__((ext_vector_type(2))) float f32x2;
#define MFMA __builtin_amdgcn_mfma_f32_16x16x32_bf16

__device__ __forceinline__ float bf2f(u16 v) {
    union { unsigned int u; float f; } x; x.u = ((unsigned int)v) << 16; return x.f;
}
__device__ __forceinline__ u16 f2bf(float f) {
    union { unsigned int u; float f; } x; x.f = f;
    unsigned int r = x.u + 0x7fff + ((x.u >> 16) & 1);
    return (u16)(r >> 16);
}
// fast ELU: t>0 ? t : exp2(t*log2e)-1  (v_exp_f32 path)
__device__ __forceinline__ float elu_fast(float t) {
    return t > 0.f ? t : (__builtin_amdgcn_exp2f(t * 1.44269504088896f) - 1.f);
}
// pack 2 f32 -> 2 fp8 (e4m3) in low 16 bits
__device__ __forceinline__ u32 pk_fp8(float a, float b) {
    return __builtin_amdgcn_cvt_pk_fp8_f32(a, b, 0u, false);
}

// K0: weight prep -> bf16 transposed layouts [c][k]; zeroes per-bucket cursors
__global__ void k_wb(const float* __restrict__ we0, const float* __restrict__ we1,
                     const float* __restrict__ wn0, const float* __restrict__ wn1,
                     u16* __restrict__ wcombt, u16* __restrict__ we1t,
                     u16* __restrict__ wn0t, u16* __restrict__ wn1t,
                     int* __restrict__ gcursor) {
    int i = blockIdx.x * 256 + threadIdx.x;
    if (i < 32768) {                       // wcombt
        int c = i >> 7, k = i & 127;
        float v;
        if (c < 128) v = we0[k * 128 + c] + we0[(256 + k) * 128 + c];
        else { int cc = c - 128; v = we0[(128 + k) * 128 + cc] - we0[(256 + k) * 128 + cc]; }
        wcombt[i] = f2bf(v);
    } else if (i < 49152) {                // we1t
        int j = i - 32768; int c = j >> 7, k = j & 127;
        we1t[j] = f2bf(we1[k * 128 + c]);
    } else if (i < 81920) {                // wn0t (k = 0..255)
        int j = i - 49152; int c = j >> 8, k = j & 255;
        wn0t[j] = f2bf(wn0[k * 128 + c]);
    } else if (i < 98304) {                // wn1t
        int j = i - 81920; int c = j >> 7, k = j & 127;
        wn1t[j] = f2bf(wn1[k * 128 + c]);
    } else if (i < 98304 + NB) {           // gcursor = 0
        gcursor[i - 98304] = 0;
    }
}

// K1 (fused): blocks [0, PQ_BLOCKS) = PQ MFMA; blocks [PQ_BLOCKS, +SCAT_BLOCKS) = bucket
// scatter. Disjoint inputs/outputs -> safe co-schedule; bscat overlaps latency-bound PQ.
__global__ __launch_bounds__(256) void k_front(const float* __restrict__ x,
                                               const u16* __restrict__ wcombt,
                                               u8* __restrict__ p8, u16* __restrict__ qb,
                                               u16* __restrict__ xb,
                                               const int* __restrict__ ei,
                                               int* __restrict__ gcursor, u32* __restrict__ ebuf) {
    int tid = threadIdx.x;
    if (blockIdx.x < PQ_BLOCKS) {
        // ======== PQ half: [P|Q] = x @ Wcomb, 128 rows/block, rt=2 per wave ========
        __shared__ u8  pq[128 * 272];
        __shared__ u16 qt[128 * 136];
        int r0 = blockIdx.x * 128;
        int wid = tid >> 6, lane = tid & 63;
        int arow = lane & 15, kblk = lane >> 4;
        int rbase = wid * 32;

        short8 a[2][4];
#pragma unroll
        for (int rt = 0; rt < 2; rt++) {
            int row_local = rbase + rt * 16 + arow;
            int nrow = r0 + row_local; if (nrow >= NN) nrow = NN - 1;
            const float* xrow = &x[(size_t)nrow * 128];
            float4 xf[8];
#pragma unroll
            for (int ks = 0; ks < 4; ks++) {
                xf[2 * ks]     = *(const float4*)&xrow[ks * 32 + kblk * 8];
                xf[2 * ks + 1] = *(const float4*)&xrow[ks * 32 + kblk * 8 + 4];
            }
            const float* xfp = (const float*)xf;
#pragma unroll
            for (int ks = 0; ks < 4; ks++) {
                short8 r;
#pragma unroll
                for (int j = 0; j < 8; j++) r[j] = (short)f2bf(xfp[ks * 8 + j]);
                a[rt][ks] = r;
                *(short8*)&xb[(size_t)nrow * 128 + ks * 32 + kblk * 8] = r;
            }
#pragma unroll
            for (int ks = 0; ks < 4; ks++)
#pragma unroll
                for (int m = 0; m < 4; m++) {
                    u16 v = (u16)pk_fp8(xfp[ks * 8 + 2 * m], xfp[ks * 8 + 2 * m + 1]);
                    *(u16*)&pq[row_local * 272 + 4 * (ks * 16 + kblk * 4 + m) + 2] = v;
                }
        }
        floatx4 acc[2][16];
#pragma unroll
        for (int rt = 0; rt < 2; rt++)
#pragma unroll
            for (int n0 = 0; n0 < 16; n0++) acc[rt][n0] = (floatx4)(0.f);
#pragma unroll
        for (int ks = 0; ks < 4; ks++)
#pragma unroll
            for (int n0 = 0; n0 < 16; n0++) {
                short8 b = *(const short8*)&wcombt[(size_t)(n0 * 16 + arow) * 128 + ks * 32 + kblk * 8];
                acc[0][n0] = MFMA(a[0][ks], b, acc[0][n0], 0, 0, 0);
                acc[1][n0] = MFMA(a[1][ks], b, acc[1][n0], 0, 0, 0);
            }
#pragma unroll
        for (int rt = 0; rt < 2; rt++)
#pragma unroll
            for (int n0 = 0; n0 < 16; n0++)
#pragma unroll
                for (int j = 0; j < 4; j++) {
                    int r = rbase + rt * 16 + kblk * 4 + j;
                    int col = n0 * 16 + arow;
                    float v = acc[rt][n0][j];
                    if (n0 < 8) pq[r * 272 + 4 * (col >> 1) + (col & 1)] = (u8)pk_fp8(v, v);
                    else        qt[r * 136 + (col - 128)] = f2bf(v);
                }
        __syncthreads();
        for (int s = tid; s < 128 * 16; s += 256) {
            int r = s >> 4, cb = (s & 15) * 16;
            int n = r0 + r;
            if (n < NN) *(short8*)&p8[(size_t)n * 256 + cb] = *(const short8*)&pq[r * 272 + cb];
        }
        for (int s = tid; s < 128 * 16; s += 256) {
            int r = s >> 4, cb = (s & 15) * 8;
            int n = r0 + r;
            if (n < NN) *(short8*)&qb[(size_t)n * 128 + cb] = *(const short8*)&qt[r * 136 + cb];
        }
    } else {
        // ======== bscat half: bucket scatter into fixed regions ========
        __shared__ int lh[NB], lbase[NB], lrank[NB];
        int bs = (blockIdx.x - PQ_BLOCKS) * 8192;
        for (int t = tid; t < NB; t += 256) { lh[t] = 0; lrank[t] = 0; }
        __syncthreads();
        int srcv[32], dstv[32];
#pragma unroll
        for (int k = 0; k < 8; k++) {
            int e = bs + k * 1024 + tid * 4;
            int4 s4, d4;
            if (e < NE) { s4 = *(const int4*)&ei[e]; d4 = *(const int4*)&ei[NE + e]; }
            else { s4 = make_int4(0, 0, 0, 0); d4 = make_int4(-1, -1, -1, -1); }
            srcv[4 * k + 0] = s4.x; srcv[4 * k + 1] = s4.y; srcv[4 * k + 2] = s4.z; srcv[4 * k + 3] = s4.w;
            dstv[4 * k + 0] = d4.x; dstv[4 * k + 1] = d4.y; dstv[4 * k + 2] = d4.z; dstv[4 * k + 3] = d4.w;
        }
#pragma unroll
        for (int i = 0; i < 32; i++)
            if (dstv[i] >= 0) atomicAdd(&lh[dstv[i] >> 7], 1);
        __syncthreads();
        for (int t = tid; t < NB; t += 256)
            if (lh[t]) lbase[t] = atomicAdd(&gcursor[t], lh[t]);
        __syncthreads();
#pragma unroll
        for (int i = 0; i < 32; i++) {
            int d = dstv[i];
            if (d >= 0) {
                int b = d >> 7;
                int r = atomicAdd(&lrank[b], 1);
                ebuf[(size_t)b * CAP + lbase[b] + r] = (u32)srcv[i] | ((u32)(d & 127) << 16);
            }
        }
    }
}

// K2: per-bucket counting sort -> per-node [obeg,oend) + srcs (block-exclusive region).
__global__ __launch_bounds__(256) void k_bsort(const u32* __restrict__ ebuf,
                                               const int* __restrict__ gcursor,
                                               int* __restrict__ obeg, int* __restrict__ oend,
                                               int* __restrict__ srcs) {
    __shared__ int hist[128], excl[128], cur[128];
    int bb = blockIdx.x;
    int tid = threadIdx.x;
    int beg = bb * CAP;
    int cnt = gcursor[bb];
    int end = beg + cnt;
    if (tid < 128) hist[tid] = 0;
    __syncthreads();
    for (int s = beg + tid; s < end; s += 256)
        atomicAdd(&hist[(ebuf[s] >> 16) & 127], 1);
    __syncthreads();
    if (tid == 0) {
        int run = 0;
        for (int i = 0; i < 128; i++) { excl[i] = run; run += hist[i]; }
    }
    __syncthreads();
    int nodebase = bb * 128;
    if (tid < 128) {
        cur[tid] = beg + excl[tid];
        int n = nodebase + tid;
        if (n < NN) {
            obeg[n] = beg + excl[tid];
            oend[n] = beg + excl[tid] + hist[tid];
        }
    }
    if (tid == 0) {
#pragma unroll
        for (int k = 0; k < 8; k++) srcs[end + k] = 0;   // pad: safe prefetch targets
    }
    __syncthreads();
    for (int s = beg + tid; s < end; s += 256) {
        u32 pe = ebuf[s];
        int dl = (pe >> 16) & 127;
        int pos = atomicAdd(&cur[dl], 1);
        srcs[pos] = (int)(pe & 0xFFFF);
    }
}

// K3: one wave per node; fp8 gathers; width-adaptive masked tail.
__global__ __launch_bounds__(256) void k_agg(const u8* __restrict__ p8, const u16* __restrict__ qb,
                                             const u16* __restrict__ xb,
                                             const int* __restrict__ obeg, const int* __restrict__ oend,
                                             const int* __restrict__ srcs,
                                             u16* __restrict__ esumx) {
    const u32* p8r = (const u32*)p8;
    int wave = threadIdx.x >> 6, lane = threadIdx.x & 63;
    int n = blockIdx.x * 4 + wave;
    if (n >= NN) return;
    int beg = obeg[n], end = oend[n];
    ushort2 qv = *(const ushort2*)(qb + (size_t)n * 128 + 2 * lane);
    float q0 = bf2f(qv.x), q1 = bf2f(qv.y);
    float e0 = 0.f, e1 = 0.f, s0 = 0.f, s1 = 0.f;
    int s = beg;
    if (end > beg) {
        int sr[8];
#pragma unroll
        for (int j = 0; j < 8; j++) sr[j] = srcs[beg + j];         // padded-safe
        for (; s + 8 <= end; s += 8) {
            u32 d[8];
#pragma unroll
            for (int j = 0; j < 8; j++) d[j] = p8r[((u32)sr[j] << 6) + (u32)lane];
            int nb = s + 8;
            if (nb < end) {
#pragma unroll
                for (int j = 0; j < 8; j++) sr[j] = srcs[nb + j];  // padded-safe
            }
#pragma unroll
            for (int j = 0; j < 8; j++) {
                f32x2 pp = __builtin_amdgcn_cvt_pk_f32_fp8(d[j], false);
                f32x2 xp = __builtin_amdgcn_cvt_pk_f32_fp8(d[j], true);
                e0 += elu_fast(pp[0] + q0);
                e1 += elu_fast(pp[1] + q1);
                s0 += xp[0]; s1 += xp[1];
            }
        }
        int rem = end - s;
        if (rem > 4) {        // masked-8 tail
            u32 d[8];
#pragma unroll
            for (int j = 0; j < 8; j++) d[j] = p8r[((u32)sr[j] << 6) + (u32)lane];
#pragma unroll
            for (int j = 0; j < 8; j++) {
                bool live = (j < rem);
                f32x2 pp = __builtin_amdgcn_cvt_pk_f32_fp8(d[j], false);
                f32x2 xp = __builtin_amdgcn_cvt_pk_f32_fp8(d[j], true);
                float c0 = elu_fast(pp[0] + q0), c1 = elu_fast(pp[1] + q1);
                e0 += live ? c0 : 0.f;
                e1 += live ? c1 : 0.f;
                s0 += live ? xp[0] : 0.f;
                s1 += live ? xp[1] : 0.f;
            }
        } else if (rem > 0) { // masked-4 tail
            u32 d[4];
#pragma unroll
            for (int j = 0; j < 4; j++) d[j] = p8r[((u32)sr[j] << 6) + (u32)lane];
#pragma unroll
            for (int j = 0; j < 4; j++) {
                bool live = (j < rem);
                f32x2 pp = __builtin_amdgcn_cvt_pk_f32_fp8(d[j], false);
                f32x2 xp = __builtin_amdgcn_cvt_pk_f32_fp8(d[j], true);
                float c0 = elu_fast(pp[0] + q0), c1 = elu_fast(pp[1] + q1);
                e0 += live ? c0 : 0.f;
                e1 += live ? c1 : 0.f;
                s0 += live ? xp[0] : 0.f;
                s1 += live ? xp[1] : 0.f;
            }
        }
    }
    float cntf = (float)(end - beg);
    float inv = 1.f / fmaxf(cntf, 1.f);
    ushort2 xo = *(const ushort2*)(xb + (size_t)n * 128 + 2 * lane);
    s0 = (s0 - cntf * bf2f(xo.x)) * inv;
    s1 = (s1 - cntf * bf2f(xo.y)) * inv;
    e0 *= inv; e1 *= inv;
    ushort2 oe = { f2bf(e0), f2bf(e1) };
    ushort2 os = { f2bf(s0), f2bf(s1) };
    *(ushort2*)(esumx + (size_t)n * 256 + 2 * lane) = oe;
    *(ushort2*)(esumx + (size_t)n * 256 + 128 + 2 * lane) = os;
}

// K4 v5: MFMA node MLP, occupancy-first. 64 rows/block (grid 782 = 3 blocks/CU),
// 4 waves x 16 PRIVATE rows each -> ZERO barriers; demand-loaded weights (L2-hot);
// per-lane A-frags prefetched; tile LDS only 17.4 KB.
__global__ __launch_bounds__(256) void k_node_mfma(const float* __restrict__ x,
                                                   const u16* __restrict__ xb,
                                                   const u16* __restrict__ esumx,
                                                   const u16* __restrict__ we1t,
                                                   const u16* __restrict__ wn0t,
                                                   const u16* __restrict__ wn1t,
                                                   float* __restrict__ out) {
    __shared__ u16 tile[64 * 136];  // 17.4 KB; per-wave-private 16-row slices
    int r0 = blockIdx.x * 64;
    int tid = threadIdx.x, wid = tid >> 6, lane = tid & 63;
    int arow = lane & 15, kblk = lane >> 4;
    int rbase = wid * 16;
    int nrow = r0 + rbase + arow; if (nrow >= NN) nrow = NN - 1;

    // per-lane global A-frags (one batch of independent loads)
    short8 a1[4], ax[4];
#pragma unroll
    for (int ks = 0; ks < 4; ks++) {
        a1[ks] = *(const short8*)&esumx[(size_t)nrow * 256 + ks * 32 + kblk * 8];
        ax[ks] = *(const short8*)&xb[(size_t)nrow * 128 + ks * 32 + kblk * 8];
    }
    // stage own wave's 16 rows of xsum' -> tile (wave-private; no barrier needed)
#pragma unroll
    for (int t = 0; t < 4; t++) {
        int idx = t * 64 + lane;               // 16 rows x 16 chunks
        int r = idx >> 4, cb = (idx & 15) * 8;
        int n = r0 + rbase + r; if (n >= NN) n = NN - 1;
        *(short8*)&tile[(rbase + r) * 136 + cb] = *(const short8*)&esumx[(size_t)n * 256 + 128 + cb];
    }

    // ---- stage 1: T = esum' @ We1 (B demand-loaded, L2-hot) ----
    floatx4 acc[8];
#pragma unroll
    for (int n0 = 0; n0 < 8; n0++) acc[n0] = (floatx4)(0.f);
#pragma unroll
    for (int ks = 0; ks < 4; ks++)
#pragma unroll
        for (int n0 = 0; n0 < 8; n0++) {
            short8 b = *(const short8*)&we1t[(size_t)(n0 * 16 + arow) * 128 + ks * 32 + kblk * 8];
            acc[n0] = MFMA(a1[ks], b, acc[n0], 0, 0, 0);
        }
    // ---- m = T + xsum' (own rows; within-wave LDS RAW ordering) ----
#pragma unroll
    for (int n0 = 0; n0 < 8; n0++)
#pragma unroll
        for (int j = 0; j < 4; j++) {
            int rloc = rbase + kblk * 4 + j;
            int col = n0 * 16 + arow;
            float m = acc[n0][j] + bf2f(tile[rloc * 136 + col]);
            tile[rloc * 136 + col] = f2bf(m);
        }
    // ---- stage 2: h = ELU(x@Wn0a + m@Wn0b) ----
#pragma unroll
    for (int n0 = 0; n0 < 8; n0++) acc[n0] = (floatx4)(0.f);
#pragma unroll
    for (int ks = 0; ks < 4; ks++) {
        short8 am = *(const short8*)&tile[(rbase + arow) * 136 + ks * 32 + kblk * 8];
#pragma unroll
        for (int n0 = 0; n0 < 8; n0++) {
            short8 bx = *(const short8*)&wn0t[(size_t)(n0 * 16 + arow) * 256 + ks * 32 + kblk * 8];
            short8 bm = *(const short8*)&wn0t[(size_t)(n0 * 16 + arow) * 256 + 128 + ks * 32 + kblk * 8];
            acc[n0] = MFMA(ax[ks], bx, acc[n0], 0, 0, 0);
            acc[n0] = MFMA(am, bm, acc[n0], 0, 0, 0);
        }
    }
    // ---- h -> tile (own rows) ----
#pragma unroll
    for (int n0 = 0; n0 < 8; n0++)
#pragma unroll
        for (int j = 0; j < 4; j++) {
            int rloc = rbase + kblk * 4 + j;
            tile[rloc * 136 + n0 * 16 + arow] = f2bf(elu_fast(acc[n0][j]));
        }
    // ---- stage 3: r = h @ Wn1 ----
#pragma unroll
    for (int n0 = 0; n0 < 8; n0++) acc[n0] = (floatx4)(0.f);
#pragma unroll
    for (int ks = 0; ks < 4; ks++) {
        short8 a = *(const short8*)&tile[(rbase + arow) * 136 + ks * 32 + kblk * 8];
#pragma unroll
        for (int n0 = 0; n0 < 8; n0++) {
            short8 b = *(const short8*)&wn1t[(size_t)(n0 * 16 + arow) * 128 + ks * 32 + kblk * 8];
            acc[n0] = MFMA(a, b, acc[n0], 0, 0, 0);
        }
    }
    // ---- r -> tile (bf16), per-wave coalesced float4 epilogue ----
#pragma unroll
    for (int n0 = 0; n0 < 8; n0++)
#pragma unroll
        for (int j = 0; j < 4; j++)
            tile[(rbase + kblk * 4 + j) * 136 + n0 * 16 + arow] = f2bf(acc[n0][j]);
#pragma unroll
    for (int t = 0; t < 8; t++) {
        int idx = t * 64 + lane;               // 16 rows x 32 float4-chunks
        int r = idx >> 5, cb = (idx & 31) * 4;
        int n = r0 + rbase + r;
        if (n < NN) {
            float4 xv = *(const float4*)&x[(size_t)n * 128 + cb];
            ushort4 tv = *(const ushort4*)&tile[(rbase + r) * 136 + cb];
            float4 o = { xv.x + bf2f(tv.x), xv.y + bf2f(tv.y), xv.z + bf2f(tv.z), xv.w + bf2f(tv.w) };
            *(float4*)&out[(size_t)n * 128 + cb] = o;
        }
    }
}

extern "C" void kernel_launch(void* const* d_in, const int* in_sizes, int n_in,
                              void* d_out, int out_size, void* d_ws, size_t ws_size,
                              hipStream_t stream) {
    const float* x       = (const float*)d_in[0];
    const int* ei        = (const int*)d_in[1];   // int64 in reference -> int32 from harness
    const float* we0     = (const float*)d_in[2];
    const float* we1     = (const float*)d_in[3];
    const float* wn0     = (const float*)d_in[4];
    const float* wn1     = (const float*)d_in[5];
    float* out           = (float*)d_out;

    char* w = (char*)d_ws;
    size_t off = 0;
    auto alloc = [&](size_t bytes) -> void* {
        off = (off + 255) & ~(size_t)255;
        void* p = w + off;
        off += bytes;
        return p;
    };
    u16*   wcombt = (u16*)alloc(256 * 128 * sizeof(u16));
    u16*   we1t   = (u16*)alloc(128 * 128 * sizeof(u16));
    u16*   wn0t   = (u16*)alloc(128 * 256 * sizeof(u16));
    u16*   wn1t   = (u16*)alloc(128 * 128 * sizeof(u16));
    u8*    p8     = (u8*)alloc((size_t)NN * 256 * sizeof(u8));
    u16*   qb     = (u16*)alloc((size_t)NN * 128 * sizeof(u16));
    u16*   xb     = (u16*)alloc((size_t)NN * 128 * sizeof(u16));
    u16*   esumx  = (u16*)alloc((size_t)NN * 256 * sizeof(u16));
    int*   gcursor= (int*)alloc(NB * sizeof(int));
    u32*   ebuf   = (u32*)alloc((size_t)NB * CAP * sizeof(u32));
    int*   obeg   = (int*)alloc((size_t)NN * sizeof(int));
    int*   oend   = (int*)alloc((size_t)NN * sizeof(int));
    int*   srcs   = (int*)alloc(((size_t)NB * CAP + 64) * sizeof(int));
    (void)ws_size; (void)in_sizes; (void)n_in; (void)out_size;  // ~78 MB of d_ws used

    k_wb<<<(98304 + NB + 255) / 256, 256, 0, stream>>>(we0, we1, wn0, wn1,
                                                       wcombt, we1t, wn0t, wn1t, gcursor);
    k_front<<<PQ_BLOCKS + SCAT_BLOCKS, 256, 0, stream>>>(x, wcombt, p8, qb, xb,
                                                         ei, gcursor, ebuf);
    k_bsort<<<NB, 256, 0, stream>>>(ebuf, gcursor, obeg, oend, srcs);
    k_agg<<<(NN + 3) / 4, 256, 0, stream>>>(p8, qb, xb, obeg, oend, srcs, esumx);
    k_node_mfma<<<(NN + 63) / 64, 256, 0, stream>>>(x, xb, esumx, we1t, wn0t, wn1t, out);
}

// Round 19
// 137.573 us; speedup vs baseline: 1.2007x; 1.2007x over previous
//
#include <hip/hip_runtime.h>
#include <hip/hip_bf16.h>

// Problem constants (from reference)
#define NN 50000
#define NE 800000
#define HD 128
#define NB 391              // buckets of 128 dst nodes: (NN+127)>>7
#define CAP 4096            // fixed bucket capacity: mean 2048, sigma ~45 -> +45 sigma
#define PQ_BLOCKS 391      // (NN+127)/128
#define SCAT_BLOCKS ((NE + 8191) / 8192)

typedef unsigned short u16;
typedef unsigned char u8;
typedef unsigned int u32;
typedef __attribute__((ext_vector_type(8))) short short8;
typedef __attribute__((ext_vector_type(4))) float floatx4;
typedef __attribute__((ext_vector_type(2))) float f32x2;
#define MFMA __builtin_amdgcn_mfma_f32_16x16x32_bf16

__device__ __forceinline__ float bf2f(u16 v) {
    union { unsigned int u; float f; } x; x.u = ((unsigned int)v) << 16; return x.f;
}
__device__ __forceinline__ u16 f2bf(float f) {
    union { unsigned int u; float f; } x; x.f = f;
    unsigned int r = x.u + 0x7fff + ((x.u >> 16) & 1);
    return (u16)(r >> 16);
}
// fast ELU: t>0 ? t : exp2(t*log2e)-1  (v_exp_f32 path)
__device__ __forceinline__ float elu_fast(float t) {
    return t > 0.f ? t : (__builtin_amdgcn_exp2f(t * 1.44269504088896f) - 1.f);
}
// pack 2 f32 -> 2 fp8 (e4m3) in low 16 bits
__device__ __forceinline__ u32 pk_fp8(float a, float b) {
    return __builtin_amdgcn_cvt_pk_fp8_f32(a, b, 0u, false);
}

// K0: weight prep -> bf16 transposed layouts [c][k]; zeroes per-bucket cursors
__global__ void k_wb(const float* __restrict__ we0, const float* __restrict__ we1,
                     const float* __restrict__ wn0, const float* __restrict__ wn1,
                     u16* __restrict__ wcombt, u16* __restrict__ we1t,
                     u16* __restrict__ wn0t, u16* __restrict__ wn1t,
                     int* __restrict__ gcursor) {
    int i = blockIdx.x * 256 + threadIdx.x;
    if (i < 32768) {                       // wcombt
        int c = i >> 7, k = i & 127;
        float v;
        if (c < 128) v = we0[k * 128 + c] + we0[(256 + k) * 128 + c];
        else { int cc = c - 128; v = we0[(128 + k) * 128 + cc] - we0[(256 + k) * 128 + cc]; }
        wcombt[i] = f2bf(v);
    } else if (i < 49152) {                // we1t
        int j = i - 32768; int c = j >> 7, k = j & 127;
        we1t[j] = f2bf(we1[k * 128 + c]);
    } else if (i < 81920) {                // wn0t (k = 0..255)
        int j = i - 49152; int c = j >> 8, k = j & 255;
        wn0t[j] = f2bf(wn0[k * 128 + c]);
    } else if (i < 98304) {                // wn1t
        int j = i - 81920; int c = j >> 7, k = j & 127;
        wn1t[j] = f2bf(wn1[k * 128 + c]);
    } else if (i < 98304 + NB) {           // gcursor = 0
        gcursor[i - 98304] = 0;
    }
}

// K1 (fused): blocks [0, PQ_BLOCKS) = PQ MFMA; blocks [PQ_BLOCKS, +SCAT_BLOCKS) = bucket
// scatter. Disjoint inputs/outputs -> safe co-schedule; bscat overlaps latency-bound PQ.
__global__ __launch_bounds__(256) void k_front(const float* __restrict__ x,
                                               const u16* __restrict__ wcombt,
                                               u8* __restrict__ p8, u16* __restrict__ qb,
                                               u16* __restrict__ xb,
                                               const int* __restrict__ ei,
                                               int* __restrict__ gcursor, u32* __restrict__ ebuf) {
    int tid = threadIdx.x;
    if (blockIdx.x < PQ_BLOCKS) {
        // ======== PQ half: [P|Q] = x @ Wcomb, 128 rows/block, rt=2 per wave ========
        __shared__ u8  pq[128 * 272];
        __shared__ u16 qt[128 * 136];
        int r0 = blockIdx.x * 128;
        int wid = tid >> 6, lane = tid & 63;
        int arow = lane & 15, kblk = lane >> 4;
        int rbase = wid * 32;

        short8 a[2][4];
#pragma unroll
        for (int rt = 0; rt < 2; rt++) {
            int row_local = rbase + rt * 16 + arow;
            int nrow = r0 + row_local; if (nrow >= NN) nrow = NN - 1;
            const float* xrow = &x[(size_t)nrow * 128];
            float4 xf[8];
#pragma unroll
            for (int ks = 0; ks < 4; ks++) {
                xf[2 * ks]     = *(const float4*)&xrow[ks * 32 + kblk * 8];
                xf[2 * ks + 1] = *(const float4*)&xrow[ks * 32 + kblk * 8 + 4];
            }
            const float* xfp = (const float*)xf;
#pragma unroll
            for (int ks = 0; ks < 4; ks++) {
                short8 r;
#pragma unroll
                for (int j = 0; j < 8; j++) r[j] = (short)f2bf(xfp[ks * 8 + j]);
                a[rt][ks] = r;
                *(short8*)&xb[(size_t)nrow * 128 + ks * 32 + kblk * 8] = r;
            }
#pragma unroll
            for (int ks = 0; ks < 4; ks++)
#pragma unroll
                for (int m = 0; m < 4; m++) {
                    u16 v = (u16)pk_fp8(xfp[ks * 8 + 2 * m], xfp[ks * 8 + 2 * m + 1]);
                    *(u16*)&pq[row_local * 272 + 4 * (ks * 16 + kblk * 4 + m) + 2] = v;
                }
        }
        floatx4 acc[2][16];
#pragma unroll
        for (int rt = 0; rt < 2; rt++)
#pragma unroll
            for (int n0 = 0; n0 < 16; n0++) acc[rt][n0] = (floatx4)(0.f);
#pragma unroll
        for (int ks = 0; ks < 4; ks++)
#pragma unroll
            for (int n0 = 0; n0 < 16; n0++) {
                short8 b = *(const short8*)&wcombt[(size_t)(n0 * 16 + arow) * 128 + ks * 32 + kblk * 8];
                acc[0][n0] = MFMA(a[0][ks], b, acc[0][n0], 0, 0, 0);
                acc[1][n0] = MFMA(a[1][ks], b, acc[1][n0], 0, 0, 0);
            }
#pragma unroll
        for (int rt = 0; rt < 2; rt++)
#pragma unroll
            for (int n0 = 0; n0 < 16; n0++)
#pragma unroll
                for (int j = 0; j < 4; j++) {
                    int r = rbase + rt * 16 + kblk * 4 + j;
                    int col = n0 * 16 + arow;
                    float v = acc[rt][n0][j];
                    if (n0 < 8) pq[r * 272 + 4 * (col >> 1) + (col & 1)] = (u8)pk_fp8(v, v);
                    else        qt[r * 136 + (col - 128)] = f2bf(v);
                }
        __syncthreads();
        for (int s = tid; s < 128 * 16; s += 256) {
            int r = s >> 4, cb = (s & 15) * 16;
            int n = r0 + r;
            if (n < NN) *(short8*)&p8[(size_t)n * 256 + cb] = *(const short8*)&pq[r * 272 + cb];
        }
        for (int s = tid; s < 128 * 16; s += 256) {
            int r = s >> 4, cb = (s & 15) * 8;
            int n = r0 + r;
            if (n < NN) *(short8*)&qb[(size_t)n * 128 + cb] = *(const short8*)&qt[r * 136 + cb];
        }
    } else {
        // ======== bscat half: bucket scatter into fixed regions ========
        __shared__ int lh[NB], lbase[NB], lrank[NB];
        int bs = (blockIdx.x - PQ_BLOCKS) * 8192;
        for (int t = tid; t < NB; t += 256) { lh[t] = 0; lrank[t] = 0; }
        __syncthreads();
        int srcv[32], dstv[32];
#pragma unroll
        for (int k = 0; k < 8; k++) {
            int e = bs + k * 1024 + tid * 4;
            int4 s4, d4;
            if (e < NE) { s4 = *(const int4*)&ei[e]; d4 = *(const int4*)&ei[NE + e]; }
            else { s4 = make_int4(0, 0, 0, 0); d4 = make_int4(-1, -1, -1, -1); }
            srcv[4 * k + 0] = s4.x; srcv[4 * k + 1] = s4.y; srcv[4 * k + 2] = s4.z; srcv[4 * k + 3] = s4.w;
            dstv[4 * k + 0] = d4.x; dstv[4 * k + 1] = d4.y; dstv[4 * k + 2] = d4.z; dstv[4 * k + 3] = d4.w;
        }
#pragma unroll
        for (int i = 0; i < 32; i++)
            if (dstv[i] >= 0) atomicAdd(&lh[dstv[i] >> 7], 1);
        __syncthreads();
        for (int t = tid; t < NB; t += 256)
            if (lh[t]) lbase[t] = atomicAdd(&gcursor[t], lh[t]);
        __syncthreads();
#pragma unroll
        for (int i = 0; i < 32; i++) {
            int d = dstv[i];
            if (d >= 0) {
                int b = d >> 7;
                int r = atomicAdd(&lrank[b], 1);
                ebuf[(size_t)b * CAP + lbase[b] + r] = (u32)srcv[i] | ((u32)(d & 127) << 16);
            }
        }
    }
}

// K2: per-bucket counting sort -> per-node [obeg,oend) + srcs (block-exclusive region).
// Zero-pads 8 slack entries so k_agg can prefetch unconditionally.
__global__ __launch_bounds__(256) void k_bsort(const u32* __restrict__ ebuf,
                                               const int* __restrict__ gcursor,
                                               int* __restrict__ obeg, int* __restrict__ oend,
                                               int* __restrict__ srcs) {
    __shared__ int hist[128], excl[128], cur[128];
    int bb = blockIdx.x;
    int tid = threadIdx.x;
    int beg = bb * CAP;
    int cnt = gcursor[bb];
    int end = beg + cnt;
    if (tid < 128) hist[tid] = 0;
    __syncthreads();
    for (int s = beg + tid; s < end; s += 256)
        atomicAdd(&hist[(ebuf[s] >> 16) & 127], 1);
    __syncthreads();
    if (tid == 0) {
        int run = 0;
        for (int i = 0; i < 128; i++) { excl[i] = run; run += hist[i]; }
    }
    __syncthreads();
    int nodebase = bb * 128;
    if (tid < 128) {
        cur[tid] = beg + excl[tid];
        int n = nodebase + tid;
        if (n < NN) {
            obeg[n] = beg + excl[tid];
            oend[n] = beg + excl[tid] + hist[tid];
        }
    }
    if (tid == 0) {
#pragma unroll
        for (int k = 0; k < 8; k++) srcs[end + k] = 0;   // pad: safe prefetch targets
    }
    __syncthreads();
    for (int s = beg + tid; s < end; s += 256) {
        u32 pe = ebuf[s];
        int dl = (pe >> 16) & 127;
        int pos = atomicAdd(&cur[dl], 1);
        srcs[pos] = (int)(pe & 0xFFFF);
    }
}

// K3: one wave per node; fp8 gathers (4 B/lane = 256 B/edge), 32-bit saddr offsets.
// Full 8-batches, then width-adaptive masked tail (4 if rem<=4, else 8).
//   esumx[n][0:128]   = esum/max(cnt,1)
//   esumx[n][128:256] = (xsum - cnt*x[n])/max(cnt,1)
__global__ __launch_bounds__(256) void k_agg(const u8* __restrict__ p8, const u16* __restrict__ qb,
                                             const u16* __restrict__ xb,
                                             const int* __restrict__ obeg, const int* __restrict__ oend,
                                             const int* __restrict__ srcs,
                                             u16* __restrict__ esumx) {
    const u32* p8r = (const u32*)p8;     // row = 64 dwords; table 12.8 MB -> 32-bit offsets ok
    int wave = threadIdx.x >> 6, lane = threadIdx.x & 63;
    int n = blockIdx.x * 4 + wave;
    if (n >= NN) return;
    int beg = obeg[n], end = oend[n];
    ushort2 qv = *(const ushort2*)(qb + (size_t)n * 128 + 2 * lane);
    float q0 = bf2f(qv.x), q1 = bf2f(qv.y);
    float e0 = 0.f, e1 = 0.f, s0 = 0.f, s1 = 0.f;
    int s = beg;
    if (end > beg) {
        int sr[8];
#pragma unroll
        for (int j = 0; j < 8; j++) sr[j] = srcs[beg + j];         // padded-safe
        for (; s + 8 <= end; s += 8) {
            u32 d[8];
#pragma unroll
            for (int j = 0; j < 8; j++) d[j] = p8r[((u32)sr[j] << 6) + (u32)lane];
            int nb = s + 8;
            if (nb < end) {
#pragma unroll
                for (int j = 0; j < 8; j++) sr[j] = srcs[nb + j];  // padded-safe
            }
#pragma unroll
            for (int j = 0; j < 8; j++) {
                f32x2 pp = __builtin_amdgcn_cvt_pk_f32_fp8(d[j], false);
                f32x2 xp = __builtin_amdgcn_cvt_pk_f32_fp8(d[j], true);
                e0 += elu_fast(pp[0] + q0);
                e1 += elu_fast(pp[1] + q1);
                s0 += xp[0]; s1 += xp[1];
            }
        }
        int rem = end - s;
        if (rem > 4) {        // masked-8 tail
            u32 d[8];
#pragma unroll
            for (int j = 0; j < 8; j++) d[j] = p8r[((u32)sr[j] << 6) + (u32)lane];
#pragma unroll
            for (int j = 0; j < 8; j++) {
                bool live = (j < rem);  // wave-uniform
                f32x2 pp = __builtin_amdgcn_cvt_pk_f32_fp8(d[j], false);
                f32x2 xp = __builtin_amdgcn_cvt_pk_f32_fp8(d[j], true);
                float c0 = elu_fast(pp[0] + q0), c1 = elu_fast(pp[1] + q1);
                e0 += live ? c0 : 0.f;
                e1 += live ? c1 : 0.f;
                s0 += live ? xp[0] : 0.f;
                s1 += live ? xp[1] : 0.f;
            }
        } else if (rem > 0) { // masked-4 tail (half the wasted compute)
            u32 d[4];
#pragma unroll
            for (int j = 0; j < 4; j++) d[j] = p8r[((u32)sr[j] << 6) + (u32)lane];
#pragma unroll
            for (int j = 0; j < 4; j++) {
                bool live = (j < rem);  // wave-uniform
                f32x2 pp = __builtin_amdgcn_cvt_pk_f32_fp8(d[j], false);
                f32x2 xp = __builtin_amdgcn_cvt_pk_f32_fp8(d[j], true);
                float c0 = elu_fast(pp[0] + q0), c1 = elu_fast(pp[1] + q1);
                e0 += live ? c0 : 0.f;
                e1 += live ? c1 : 0.f;
                s0 += live ? xp[0] : 0.f;
                s1 += live ? xp[1] : 0.f;
            }
        }
    }
    float cntf = (float)(end - beg);
    float inv = 1.f / fmaxf(cntf, 1.f);
    ushort2 xo = *(const ushort2*)(xb + (size_t)n * 128 + 2 * lane);  // own x (bf16)
    s0 = (s0 - cntf * bf2f(xo.x)) * inv;
    s1 = (s1 - cntf * bf2f(xo.y)) * inv;
    e0 *= inv; e1 *= inv;
    ushort2 oe = { f2bf(e0), f2bf(e1) };
    ushort2 os = { f2bf(s0), f2bf(s1) };
    *(ushort2*)(esumx + (size_t)n * 256 + 2 * lane) = oe;
    *(ushort2*)(esumx + (size_t)n * 256 + 128 + 2 * lane) = os;
}

// K4: MFMA node MLP (r16 best config). 128 rows/block, 4 waves; wave owns rows
// end-to-end (rt=2: 16 MFMA chains/wave, 2x B-amortization), no barriers until
// epilogue, all global inputs prefetched at entry.
__global__ __launch_bounds__(256, 2) void k_node_mfma(const float* __restrict__ x,
                                                      const u16* __restrict__ xb,
                                                      const u16* __restrict__ esumx,
                                                      const u16* __restrict__ we1t,
                                                      const u16* __restrict__ wn0t,
                                                      const u16* __restrict__ wn1t,
                                                      float* __restrict__ out) {
    __shared__ u16 tile[128 * 136];
    int r0 = blockIdx.x * 128;
    int tid = threadIdx.x, wid = tid >> 6, lane = tid & 63;
    int arow = lane & 15, kblk = lane >> 4;
    int rbase = wid * 32;
    int nrow[2];
#pragma unroll
    for (int rt = 0; rt < 2; rt++) {
        int n = r0 + rbase + rt * 16 + arow; if (n >= NN) n = NN - 1;
        nrow[rt] = n;
    }
    short8 stg[8];
#pragma unroll
    for (int t = 0; t < 8; t++) {
        int idx = t * 64 + lane;
        int r = idx >> 4, cb = (idx & 15) * 8;
        int n = r0 + rbase + r; if (n >= NN) n = NN - 1;
        stg[t] = *(const short8*)&esumx[(size_t)n * 256 + 128 + cb];
    }
    short8 a1[2][4], ax[2][4];
#pragma unroll
    for (int rt = 0; rt < 2; rt++)
#pragma unroll
        for (int ks = 0; ks < 4; ks++) {
            a1[rt][ks] = *(const short8*)&esumx[(size_t)nrow[rt] * 256 + ks * 32 + kblk * 8];
            ax[rt][ks] = *(const short8*)&xb[(size_t)nrow[rt] * 128 + ks * 32 + kblk * 8];
        }
#pragma unroll
    for (int t = 0; t < 8; t++) {
        int idx = t * 64 + lane;
        int r = rbase + (idx >> 4), cb = (idx & 15) * 8;
        *(short8*)&tile[r * 136 + cb] = stg[t];
    }
    floatx4 acc[2][8];
#pragma unroll
    for (int rt = 0; rt < 2; rt++)
#pragma unroll
        for (int n0 = 0; n0 < 8; n0++) acc[rt][n0] = (floatx4)(0.f);
#pragma unroll
    for (int ks = 0; ks < 4; ks++)
#pragma unroll
        for (int n0 = 0; n0 < 8; n0++) {
            short8 b = *(const short8*)&we1t[(size_t)(n0 * 16 + arow) * 128 + ks * 32 + kblk * 8];
            acc[0][n0] = MFMA(a1[0][ks], b, acc[0][n0], 0, 0, 0);
            acc[1][n0] = MFMA(a1[1][ks], b, acc[1][n0], 0, 0, 0);
        }
#pragma unroll
    for (int rt = 0; rt < 2; rt++)
#pragma unroll
        for (int n0 = 0; n0 < 8; n0++)
#pragma unroll
            for (int j = 0; j < 4; j++) {
                int rloc = rbase + rt * 16 + kblk * 4 + j;
                int col = n0 * 16 + arow;
                float m = acc[rt][n0][j] + bf2f(tile[rloc * 136 + col]);
                tile[rloc * 136 + col] = f2bf(m);
            }
#pragma unroll
    for (int rt = 0; rt < 2; rt++)
#pragma unroll
        for (int n0 = 0; n0 < 8; n0++) acc[rt][n0] = (floatx4)(0.f);
#pragma unroll
    for (int ks = 0; ks < 4; ks++) {
        short8 am[2];
#pragma unroll
        for (int rt = 0; rt < 2; rt++)
            am[rt] = *(const short8*)&tile[(rbase + rt * 16 + arow) * 136 + ks * 32 + kblk * 8];
#pragma unroll
        for (int n0 = 0; n0 < 8; n0++) {
            short8 bx = *(const short8*)&wn0t[(size_t)(n0 * 16 + arow) * 256 + ks * 32 + kblk * 8];
            short8 bm = *(const short8*)&wn0t[(size_t)(n0 * 16 + arow) * 256 + 128 + ks * 32 + kblk * 8];
#pragma unroll
            for (int rt = 0; rt < 2; rt++) {
                acc[rt][n0] = MFMA(ax[rt][ks], bx, acc[rt][n0], 0, 0, 0);
                acc[rt][n0] = MFMA(am[rt], bm, acc[rt][n0], 0, 0, 0);
            }
        }
    }
#pragma unroll
    for (int rt = 0; rt < 2; rt++)
#pragma unroll
        for (int n0 = 0; n0 < 8; n0++)
#pragma unroll
            for (int j = 0; j < 4; j++) {
                int rloc = rbase + rt * 16 + kblk * 4 + j;
                tile[rloc * 136 + n0 * 16 + arow] = f2bf(elu_fast(acc[rt][n0][j]));
            }
#pragma unroll
    for (int rt = 0; rt < 2; rt++)
#pragma unroll
        for (int n0 = 0; n0 < 8; n0++) acc[rt][n0] = (floatx4)(0.f);
#pragma unroll
    for (int ks = 0; ks < 4; ks++) {
        short8 a[2];
#pragma unroll
        for (int rt = 0; rt < 2; rt++)
            a[rt] = *(const short8*)&tile[(rbase + rt * 16 + arow) * 136 + ks * 32 + kblk * 8];
#pragma unroll
        for (int n0 = 0; n0 < 8; n0++) {
            short8 b = *(const short8*)&wn1t[(size_t)(n0 * 16 + arow) * 128 + ks * 32 + kblk * 8];
            acc[0][n0] = MFMA(a[0], b, acc[0][n0], 0, 0, 0);
            acc[1][n0] = MFMA(a[1], b, acc[1][n0], 0, 0, 0);
        }
    }
#pragma unroll
    for (int rt = 0; rt < 2; rt++)
#pragma unroll
        for (int n0 = 0; n0 < 8; n0++)
#pragma unroll
            for (int j = 0; j < 4; j++)
                tile[(rbase + rt * 16 + kblk * 4 + j) * 136 + n0 * 16 + arow] = f2bf(acc[rt][n0][j]);
#pragma unroll
    for (int t = 0; t < 16; t++) {
        int idx = t * 64 + lane;
        int r = idx >> 5, cb = (idx & 31) * 4;
        int n = r0 + rbase + r;
        if (n < NN) {
            float4 xv = *(const float4*)&x[(size_t)n * 128 + cb];
            ushort4 tv = *(const ushort4*)&tile[(rbase + r) * 136 + cb];
            float4 o = { xv.x + bf2f(tv.x), xv.y + bf2f(tv.y), xv.z + bf2f(tv.z), xv.w + bf2f(tv.w) };
            *(float4*)&out[(size_t)n * 128 + cb] = o;
        }
    }
}

extern "C" void kernel_launch(void* const* d_in, const int* in_sizes, int n_in,
                              void* d_out, int out_size, void* d_ws, size_t ws_size,
                              hipStream_t stream) {
    const float* x       = (const float*)d_in[0];
    const int* ei        = (const int*)d_in[1];   // int64 in reference -> int32 from harness
    const float* we0     = (const float*)d_in[2];
    const float* we1     = (const float*)d_in[3];
    const float* wn0     = (const float*)d_in[4];
    const float* wn1     = (const float*)d_in[5];
    float* out           = (float*)d_out;

    char* w = (char*)d_ws;
    size_t off = 0;
    auto alloc = [&](size_t bytes) -> void* {
        off = (off + 255) & ~(size_t)255;
        void* p = w + off;
        off += bytes;
        return p;
    };
    u16*   wcombt = (u16*)alloc(256 * 128 * sizeof(u16));
    u16*   we1t   = (u16*)alloc(128 * 128 * sizeof(u16));
    u16*   wn0t   = (u16*)alloc(128 * 256 * sizeof(u16));
    u16*   wn1t   = (u16*)alloc(128 * 128 * sizeof(u16));
    u8*    p8     = (u8*)alloc((size_t)NN * 256 * sizeof(u8));
    u16*   qb     = (u16*)alloc((size_t)NN * 128 * sizeof(u16));
    u16*   xb     = (u16*)alloc((size_t)NN * 128 * sizeof(u16));
    u16*   esumx  = (u16*)alloc((size_t)NN * 256 * sizeof(u16));
    int*   gcursor= (int*)alloc(NB * sizeof(int));
    u32*   ebuf   = (u32*)alloc((size_t)NB * CAP * sizeof(u32));
    int*   obeg   = (int*)alloc((size_t)NN * sizeof(int));
    int*   oend   = (int*)alloc((size_t)NN * sizeof(int));
    int*   srcs   = (int*)alloc(((size_t)NB * CAP + 64) * sizeof(int));
    (void)ws_size; (void)in_sizes; (void)n_in; (void)out_size;  // ~78 MB of d_ws used

    k_wb<<<(98304 + NB + 255) / 256, 256, 0, stream>>>(we0, we1, wn0, wn1,
                                                       wcombt, we1t, wn0t, wn1t, gcursor);
    k_front<<<PQ_BLOCKS + SCAT_BLOCKS, 256, 0, stream>>>(x, wcombt, p8, qb, xb,
                                                         ei, gcursor, ebuf);
    k_bsort<<<NB, 256, 0, stream>>>(ebuf, gcursor, obeg, oend, srcs);
    k_agg<<<(NN + 3) / 4, 256, 0, stream>>>(p8, qb, xb, obeg, oend, srcs, esumx);
    k_node_mfma<<<(NN + 127) / 128, 256, 0, stream>>>(x, xb, esumx, we1t, wn0t, wn1t, out);
}